// Round 1
// baseline (2697.049 us; speedup 1.0000x reference)
//
#include <hip/hip_runtime.h>
#include <hip/hip_bf16.h>
#include <cstdint>
#include <cstddef>

// Problem constants
#define B_  32
#define T_  128
#define E_  4096
#define H_  32
#define DK_ 128
#define F_  16384
#define M_  4096   // B_*T_

typedef __bf16 bf16x8 __attribute__((ext_vector_type(8)));
typedef float  f32x4  __attribute__((ext_vector_type(4)));

__device__ __forceinline__ unsigned short f2bf(float f) {
  __bf16 h = (__bf16)f;
  return __builtin_bit_cast(unsigned short, h);
}

// async global->LDS, 16B per lane. LDS dest = wave-uniform base + lane*16.
__device__ __forceinline__ void g2l16(const void* g, void* l) {
  __builtin_amdgcn_global_load_lds((__attribute__((address_space(1))) void*)g,
                                   (__attribute__((address_space(3))) void*)l,
                                   16, 0, 0);
}

// ---------------------------------------------------------------- cvt fp32->bf16
__global__ __launch_bounds__(256) void cvt_bf16_kernel(const float* __restrict__ in,
                                                       unsigned short* __restrict__ out) {
  int i = (blockIdx.x * 256 + threadIdx.x) * 8;
  float4 a = *(const float4*)(in + i);
  float4 b = *(const float4*)(in + i + 4);
  union { unsigned short u[8]; uint4 v; } p;
  p.u[0] = f2bf(a.x); p.u[1] = f2bf(a.y); p.u[2] = f2bf(a.z); p.u[3] = f2bf(a.w);
  p.u[4] = f2bf(b.x); p.u[5] = f2bf(b.y); p.u[6] = f2bf(b.z); p.u[7] = f2bf(b.w);
  *(uint4*)(out + i) = p.v;
}

// ------------------------------------------- transpose + cvt: in (R,C) f32 -> out (C,R) bf16
__global__ __launch_bounds__(256) void tcvt_kernel(const float* __restrict__ in,
                                                   unsigned short* __restrict__ out,
                                                   int R, int C) {
  __shared__ float tile[64][65];
  int tx = threadIdx.x & 63;
  int ty = threadIdx.x >> 6;
  int c0 = blockIdx.x * 64;
  int r0 = blockIdx.y * 64;
#pragma unroll
  for (int i = 0; i < 16; ++i) {
    int r = ty + i * 4;
    tile[r][tx] = in[(size_t)(r0 + r) * C + c0 + tx];
  }
  __syncthreads();
#pragma unroll
  for (int i = 0; i < 16; ++i) {
    int rr = ty + i * 4;
    out[(size_t)(c0 + rr) * R + r0 + tx] = f2bf(tile[tx][rr]);
  }
}

// ---------------------------------------------------------------- GEMM C = A @ Bt^T + bias
// A: (Mdim,Kdim) bf16 row-major. Bt: (Ndim,Kdim) bf16 row-major (i.e. W transposed).
// 128x128 block tile, BK=64, 4 waves each 64x64 (4x4 of 16x16x32 MFMA).
// LDS chunk XOR-swizzle: slot (m, c') holds global chunk (m, c' ^ (m&7)) -> conflict-free
// ds_read_b128 AND intact wave-contiguous global_load_lds staging.
enum { EPI_F32 = 0, EPI_RELU_BF16 = 1, EPI_QK = 2 };

template <int EPI>
__global__ __launch_bounds__(256) void gemm_bt(const unsigned short* __restrict__ A,
                                               const unsigned short* __restrict__ Bt,
                                               const float* __restrict__ bias,
                                               void* __restrict__ outp,
                                               int Mdim, int Ndim, int Kdim) {
  __shared__ alignas(16) unsigned short As[128 * 64];
  __shared__ alignas(16) unsigned short Bs[128 * 64];
  const int tid  = threadIdx.x;
  const int wid  = tid >> 6;
  const int lane = tid & 63;
  const int quad = lane >> 4;
  const int l16  = lane & 15;
  const int bn0  = blockIdx.x * 128;
  const int bm0  = blockIdx.y * 128;
  const int wm   = (wid >> 1) * 64;
  const int wn   = (wid & 1) * 64;

  unsigned aoff[4], boff[4], lbase[4];
#pragma unroll
  for (int r = 0; r < 4; ++r) {
    int s = r * 256 + tid;          // chunk slot 0..1023
    int m = s >> 3, cp = s & 7;
    int c = cp ^ (m & 7);           // source chunk within the row
    aoff[r]  = (unsigned)(bm0 + m) * (unsigned)Kdim + (unsigned)(c * 8);
    boff[r]  = (unsigned)(bn0 + m) * (unsigned)Kdim + (unsigned)(c * 8);
    lbase[r] = (unsigned)(r * 256 + wid * 64) * 8;  // ushort offset of wave's slot 0
  }

  f32x4 zero = {0.f, 0.f, 0.f, 0.f};
  f32x4 acc[4][4];
#pragma unroll
  for (int i = 0; i < 4; ++i)
#pragma unroll
    for (int j = 0; j < 4; ++j) acc[i][j] = zero;

  for (int kt = 0; kt < Kdim; kt += 64) {
#pragma unroll
    for (int r = 0; r < 4; ++r) {
      g2l16(A + aoff[r] + kt, &As[lbase[r]]);
      g2l16(Bt + boff[r] + kt, &Bs[lbase[r]]);
    }
    __syncthreads();
#pragma unroll
    for (int kk = 0; kk < 2; ++kk) {
      bf16x8 af[4], bfr[4];
#pragma unroll
      for (int mi = 0; mi < 4; ++mi) {
        int row = wm + mi * 16 + l16;
        int cp  = (kk * 4 + quad) ^ (row & 7);
        af[mi]  = *(const bf16x8*)&As[row * 64 + cp * 8];
      }
#pragma unroll
      for (int ni = 0; ni < 4; ++ni) {
        int row = wn + ni * 16 + l16;
        int cp  = (kk * 4 + quad) ^ (row & 7);
        bfr[ni] = *(const bf16x8*)&Bs[row * 64 + cp * 8];
      }
#pragma unroll
      for (int mi = 0; mi < 4; ++mi)
#pragma unroll
        for (int ni = 0; ni < 4; ++ni)
          acc[mi][ni] = __builtin_amdgcn_mfma_f32_16x16x32_bf16(af[mi], bfr[ni],
                                                                acc[mi][ni], 0, 0, 0);
    }
    __syncthreads();
  }

  float bv[4];
#pragma unroll
  for (int ni = 0; ni < 4; ++ni) bv[ni] = bias[bn0 + wn + ni * 16 + l16];

#pragma unroll
  for (int mi = 0; mi < 4; ++mi) {
#pragma unroll
    for (int ni = 0; ni < 4; ++ni) {
      int n = bn0 + wn + ni * 16 + l16;
#pragma unroll
      for (int r = 0; r < 4; ++r) {
        int m   = bm0 + wm + mi * 16 + quad * 4 + r;
        float v = acc[mi][ni][r] + bv[ni];
        if (EPI == EPI_F32) {
          ((float*)outp)[(size_t)m * Ndim + n] = v;
        } else if (EPI == EPI_RELU_BF16) {
          ((unsigned short*)outp)[(size_t)m * Ndim + n] = f2bf(fmaxf(v, 0.f));
        } else {  // EPI_QK: scatter (m=b*T+t, n=h*DK+dk) -> (b,h,t,dk)
          int bb = m >> 7, tt = m & 127, hh = n >> 7, dk = n & 127;
          ((unsigned short*)outp)[((size_t)(bb * H_ + hh) * T_ + tt) * DK_ + dk] = f2bf(v);
        }
      }
    }
  }
}

// --------------------------- attention: S = Q K^T / sqrt(DK), softmax rows, write (b,t,h,t2)
// one block per (b,h); Q,K are contiguous 128x128 bf16 blocks in (B,H,T,DK) layout.
__global__ __launch_bounds__(256) void attn_kernel(const unsigned short* __restrict__ qb,
                                                   const unsigned short* __restrict__ kb,
                                                   unsigned short* __restrict__ attn) {
  __shared__ alignas(16) unsigned short Qs[128 * 128];
  __shared__ alignas(16) unsigned short Ks[128 * 128];
  const int tid  = threadIdx.x;
  const int wid  = tid >> 6;
  const int lane = tid & 63;
  const int quad = lane >> 4;
  const int l16  = lane & 15;
  const int bx   = blockIdx.x;
  const int b    = bx >> 5;
  const int h    = bx & 31;
  const unsigned short* gq = qb + (size_t)bx * (T_ * DK_);
  const unsigned short* gk = kb + (size_t)bx * (T_ * DK_);

  // stage: 2048 16B chunks per matrix, swizzle c' = c ^ (m&15)
#pragma unroll
  for (int r = 0; r < 8; ++r) {
    int s = r * 256 + tid;
    int m = s >> 4, cp = s & 15;
    int c = cp ^ (m & 15);
    unsigned lb = (unsigned)(r * 256 + wid * 64) * 8;
    g2l16(gq + m * 128 + c * 8, &Qs[lb]);
    g2l16(gk + m * 128 + c * 8, &Ks[lb]);
  }
  __syncthreads();

  f32x4 zero = {0.f, 0.f, 0.f, 0.f};
  f32x4 acc[2][8];
#pragma unroll
  for (int i = 0; i < 2; ++i)
#pragma unroll
    for (int j = 0; j < 8; ++j) acc[i][j] = zero;

#pragma unroll
  for (int st = 0; st < 4; ++st) {
    bf16x8 a[2], bfr[8];
#pragma unroll
    for (int mi = 0; mi < 2; ++mi) {
      int row = wid * 32 + mi * 16 + l16;
      int cp  = (st * 4 + quad) ^ (row & 15);
      a[mi]   = *(const bf16x8*)&Qs[row * 128 + cp * 8];
    }
#pragma unroll
    for (int ni = 0; ni < 8; ++ni) {
      int row = ni * 16 + l16;
      int cp  = (st * 4 + quad) ^ (row & 15);
      bfr[ni] = *(const bf16x8*)&Ks[row * 128 + cp * 8];
    }
#pragma unroll
    for (int mi = 0; mi < 2; ++mi)
#pragma unroll
      for (int ni = 0; ni < 8; ++ni)
        acc[mi][ni] = __builtin_amdgcn_mfma_f32_16x16x32_bf16(a[mi], bfr[ni],
                                                              acc[mi][ni], 0, 0, 0);
  }

  const float scale = 0.08838834764831845f;  // 1/sqrt(128)
#pragma unroll
  for (int mi = 0; mi < 2; ++mi) {
#pragma unroll
    for (int r = 0; r < 4; ++r) {
      float v[8];
      float mx = -1e30f;
#pragma unroll
      for (int ni = 0; ni < 8; ++ni) {
        v[ni] = acc[mi][ni][r] * scale;
        mx    = fmaxf(mx, v[ni]);
      }
      mx = fmaxf(mx, __shfl_xor(mx, 1, 64));
      mx = fmaxf(mx, __shfl_xor(mx, 2, 64));
      mx = fmaxf(mx, __shfl_xor(mx, 4, 64));
      mx = fmaxf(mx, __shfl_xor(mx, 8, 64));
      float sum = 0.f;
#pragma unroll
      for (int ni = 0; ni < 8; ++ni) {
        v[ni] = __expf(v[ni] - mx);
        sum += v[ni];
      }
      sum += __shfl_xor(sum, 1, 64);
      sum += __shfl_xor(sum, 2, 64);
      sum += __shfl_xor(sum, 4, 64);
      sum += __shfl_xor(sum, 8, 64);
      float inv = 1.0f / sum;
      int rowg  = wid * 32 + mi * 16 + quad * 4 + r;
      size_t base = ((size_t)b * T_ + rowg) * E_ + h * T_;
#pragma unroll
      for (int ni = 0; ni < 8; ++ni)
        attn[base + ni * 16 + l16] = f2bf(v[ni] * inv);
    }
  }
}

// --------------------------------- LN(a + bsrc)*g + beta ; optional bf16 copy of output
__global__ __launch_bounds__(256) void ln_kernel(const float* __restrict__ a,
                                                 const float* __restrict__ bsrc,
                                                 const float* __restrict__ g,
                                                 const float* __restrict__ bet,
                                                 float* __restrict__ out32,
                                                 unsigned short* __restrict__ out16) {
  const int row = blockIdx.x;
  const int tid = threadIdx.x;
  const float* pa = a + (size_t)row * E_;
  const float* pb = bsrc + (size_t)row * E_;
  float4 xv[4];
  float s = 0.f, ss = 0.f;
#pragma unroll
  for (int i = 0; i < 4; ++i) {
    int c = tid * 4 + i * 1024;
    float4 va = *(const float4*)(pa + c);
    float4 vb = *(const float4*)(pb + c);
    float4 x;
    x.x = va.x + vb.x; x.y = va.y + vb.y; x.z = va.z + vb.z; x.w = va.w + vb.w;
    xv[i] = x;
    s  += x.x + x.y + x.z + x.w;
    ss += x.x * x.x + x.y * x.y + x.z * x.z + x.w * x.w;
  }
#pragma unroll
  for (int m = 32; m >= 1; m >>= 1) {
    s  += __shfl_xor(s, m, 64);
    ss += __shfl_xor(ss, m, 64);
  }
  __shared__ float red[8];
  int wid = tid >> 6, lane = tid & 63;
  if (lane == 0) { red[wid] = s; red[4 + wid] = ss; }
  __syncthreads();
  s  = red[0] + red[1] + red[2] + red[3];
  ss = red[4] + red[5] + red[6] + red[7];
  float mean = s * (1.0f / 4096.0f);
  float var  = ss * (1.0f / 4096.0f) - mean * mean;
  float rstd = rsqrtf(var + 1e-5f);
#pragma unroll
  for (int i = 0; i < 4; ++i) {
    int c = tid * 4 + i * 1024;
    float4 gv = *(const float4*)(g + c);
    float4 bv = *(const float4*)(bet + c);
    float4 y;
    y.x = (xv[i].x - mean) * rstd * gv.x + bv.x;
    y.y = (xv[i].y - mean) * rstd * gv.y + bv.y;
    y.z = (xv[i].z - mean) * rstd * gv.z + bv.z;
    y.w = (xv[i].w - mean) * rstd * gv.w + bv.w;
    *(float4*)(out32 + (size_t)row * E_ + c) = y;
    if (out16) {
      ushort4 u;
      u.x = f2bf(y.x); u.y = f2bf(y.y); u.z = f2bf(y.z); u.w = f2bf(y.w);
      *(ushort4*)(out16 + (size_t)row * E_ + c) = u;
    }
  }
}

// ---------------------------------------------------------------- launch
extern "C" void kernel_launch(void* const* d_in, const int* in_sizes, int n_in,
                              void* d_out, int out_size, void* d_ws, size_t ws_size,
                              hipStream_t stream) {
  const float* x     = (const float*)d_in[0];
  const float* wq    = (const float*)d_in[1];
  const float* bq    = (const float*)d_in[2];
  const float* wk    = (const float*)d_in[3];
  const float* bk    = (const float*)d_in[4];
  // d_in[5]=wv, d_in[6]=bv : unused by the reference
  const float* wo    = (const float*)d_in[7];
  const float* bo    = (const float*)d_in[8];
  const float* w1    = (const float*)d_in[9];
  const float* b1    = (const float*)d_in[10];
  const float* w2    = (const float*)d_in[11];
  const float* b2    = (const float*)d_in[12];
  const float* g1    = (const float*)d_in[13];
  const float* beta1 = (const float*)d_in[14];
  const float* g2    = (const float*)d_in[15];
  const float* beta2 = (const float*)d_in[16];

  // workspace layout (448 MiB total)
  char* ws = (char*)d_ws;
  const size_t SZ_ME_BF = (size_t)M_ * E_ * 2;   //  33,554,432
  const size_t SZ_EF_BF = (size_t)E_ * F_ * 2;   // 134,217,728
  const size_t SZ_ME_F  = (size_t)M_ * E_ * 4;   //  67,108,864
  unsigned short* xb   = (unsigned short*)ws;                   // R0
  unsigned short* wbuf = (unsigned short*)(ws + SZ_ME_BF);      // R1 (reused 5x)
  char* r2 = ws + SZ_ME_BF + SZ_EF_BF;                          // R2: qb+kb / o / f
  char* r3 = r2 + SZ_ME_F;                                      // R3: attn / x1b
  char* r4 = r3 + SZ_ME_BF;                                     // R4: x1 fp32
  char* r5 = r4 + SZ_ME_F;                                      // R5: h bf16

  unsigned short* qb   = (unsigned short*)r2;
  unsigned short* kb   = (unsigned short*)(r2 + SZ_ME_BF);
  unsigned short* attn = (unsigned short*)r3;
  float*          o    = (float*)r2;
  float*          x1   = (float*)r4;
  unsigned short* x1b  = (unsigned short*)r3;
  unsigned short* hbuf = (unsigned short*)r5;
  float*          fbuf = (float*)r2;

  // x -> bf16
  cvt_bf16_kernel<<<(M_ * E_) / (256 * 8), 256, 0, stream>>>(x, xb);

  // q = x@wq + bq  -> (B,H,T,DK) bf16
  tcvt_kernel<<<dim3(E_ / 64, E_ / 64), 256, 0, stream>>>(wq, wbuf, E_, E_);
  gemm_bt<EPI_QK><<<dim3(E_ / 128, M_ / 128), 256, 0, stream>>>(xb, wbuf, bq, qb, M_, E_, E_);

  // k = x@wk + bk
  tcvt_kernel<<<dim3(E_ / 64, E_ / 64), 256, 0, stream>>>(wk, wbuf, E_, E_);
  gemm_bt<EPI_QK><<<dim3(E_ / 128, M_ / 128), 256, 0, stream>>>(xb, wbuf, bk, kb, M_, E_, E_);

  // attn = softmax(qk^T/sqrt(dk)) in (B,T,H*T) layout
  attn_kernel<<<B_ * H_, 256, 0, stream>>>(qb, kb, attn);

  // o = attn@wo + bo (fp32)
  tcvt_kernel<<<dim3(E_ / 64, E_ / 64), 256, 0, stream>>>(wo, wbuf, E_, E_);
  gemm_bt<EPI_F32><<<dim3(E_ / 128, M_ / 128), 256, 0, stream>>>(attn, wbuf, bo, o, M_, E_, E_);

  // x1 = LN(x + o)
  ln_kernel<<<M_, 256, 0, stream>>>(x, o, g1, beta1, x1, x1b);

  // h = relu(x1@w1 + b1) bf16
  tcvt_kernel<<<dim3(F_ / 64, E_ / 64), 256, 0, stream>>>(w1, wbuf, E_, F_);
  gemm_bt<EPI_RELU_BF16><<<dim3(F_ / 128, M_ / 128), 256, 0, stream>>>(x1b, wbuf, b1, hbuf, M_, F_, E_);

  // f = h@w2 + b2 (fp32)
  tcvt_kernel<<<dim3(E_ / 64, F_ / 64), 256, 0, stream>>>(w2, wbuf, F_, E_);
  gemm_bt<EPI_F32><<<dim3(E_ / 128, M_ / 128), 256, 0, stream>>>(hbuf, wbuf, b2, fbuf, M_, E_, F_);

  // out = LN(x1 + f)
  ln_kernel<<<M_, 256, 0, stream>>>(x1, fbuf, g2, beta2, (float*)d_out, nullptr);
}